// Round 1
// baseline (1097.591 us; speedup 1.0000x reference)
//
#include <hip/hip_runtime.h>

#define NUSR 60000
#define NITM 40000
#define NN   100000
#define EE   2000000
#define HD   128
#define RROWS 8
#define NEG_BIG (-3.402823466e+38f)

// ---------------- transpose 128x128 (weights) ----------------
__global__ void transpose128(const float* __restrict__ in, float* __restrict__ out) {
    __shared__ float tile[32][33];
    int bx = blockIdx.x * 32, by = blockIdx.y * 32;
    int tx = threadIdx.x, ty = threadIdx.y;   // block (32,8)
    #pragma unroll
    for (int i = 0; i < 32; i += 8)
        tile[ty + i][tx] = in[(by + ty + i) * HD + bx + tx];
    __syncthreads();
    #pragma unroll
    for (int i = 0; i < 32; i += 8)
        out[(bx + ty + i) * HD + by + tx] = tile[tx][ty + i];
}

// ---------------- CSR build ----------------
__global__ void count_k(const int* __restrict__ dst, int* __restrict__ cnt, int e) {
    int i = blockIdx.x * blockDim.x + threadIdx.x;
    if (i < e) atomicAdd(&cnt[dst[i]], 1);
}

// block-level inclusive scan (1024 threads), writes exclusive partials + block sums
__global__ void scan1_k(const int* __restrict__ cnt, int* __restrict__ off,
                        int* __restrict__ bsum, int n) {
    __shared__ int s[1024];
    int t = threadIdx.x;
    int i = blockIdx.x * 1024 + t;
    int v = (i < n) ? cnt[i] : 0;
    s[t] = v;
    __syncthreads();
    for (int d = 1; d < 1024; d <<= 1) {
        int add = (t >= d) ? s[t - d] : 0;
        __syncthreads();
        s[t] += add;
        __syncthreads();
    }
    if (i < n) off[i] = s[t] - v;          // exclusive, block-local
    if (t == 1023) bsum[blockIdx.x] = s[1023];
}

__global__ void scan2_k(const int* __restrict__ bsum, int* __restrict__ bbase,
                        int nb, int* __restrict__ off, int n) {
    __shared__ int s[128];
    int t = threadIdx.x;                    // 128 threads, nb <= 128
    int v = (t < nb) ? bsum[t] : 0;
    s[t] = v;
    __syncthreads();
    for (int d = 1; d < 128; d <<= 1) {
        int add = (t >= d) ? s[t - d] : 0;
        __syncthreads();
        s[t] += add;
        __syncthreads();
    }
    if (t < nb) bbase[t] = s[t] - v;        // exclusive block bases
    if (t == 127) off[n] = s[127];          // grand total
}

__global__ void scan3_k(int* __restrict__ off, const int* __restrict__ bbase,
                        int* __restrict__ cur, int n) {
    int i = blockIdx.x * 1024 + threadIdx.x;
    if (i < n) {
        int o = off[i] + bbase[blockIdx.x];
        off[i] = o;
        cur[i] = o;
    }
}

__global__ void scatter_k(const int* __restrict__ src, const int* __restrict__ dst,
                          int* __restrict__ cur, int* __restrict__ csr, int e) {
    int i = blockIdx.x * blockDim.x + threadIdx.x;
    if (i < e) {
        int p = atomicAdd(&cur[dst[i]], 1);
        csr[p] = src[i];
    }
}

// ---------------- input projection: h0 = x @ wT + b (per node type) ----------
__global__ void proj_k(const float* __restrict__ x,
                       const float* __restrict__ wuT, const float* __restrict__ bu,
                       const float* __restrict__ wiT, const float* __restrict__ bi,
                       float* __restrict__ h0) {
    int col  = threadIdx.x;                 // 128 threads
    int row0 = blockIdx.x * RROWS;          // NUSR % RROWS == 0 -> uniform branch
    const float* __restrict__ wT = (row0 < NUSR) ? wuT : wiT;
    float b = (row0 < NUSR) ? bu[col] : bi[col];
    float acc[RROWS];
    #pragma unroll
    for (int r = 0; r < RROWS; ++r) acc[r] = 0.0f;
    #pragma unroll 4
    for (int k = 0; k < HD; ++k) {
        float wv = wT[k * HD + col];
        #pragma unroll
        for (int r = 0; r < RROWS; ++r)
            acc[r] += x[(row0 + r) * HD + k] * wv;   // uniform address -> s_load
    }
    #pragma unroll
    for (int r = 0; r < RROWS; ++r)
        h0[(row0 + r) * HD + col] = acc[r] + b;
}

// ---------------- segment max over in-edges ----------------
__global__ void agg_k(const float* __restrict__ h, const int* __restrict__ off,
                      const int* __restrict__ csr, float* __restrict__ agg) {
    int n = blockIdx.x;
    int f = threadIdx.x;                    // 128 threads, coalesced 512B rows
    int s0 = off[n], s1 = off[n + 1];
    float m = NEG_BIG;
    for (int j = s0; j < s1; ++j) {
        int r = csr[j];                     // uniform -> scalar load
        m = fmaxf(m, h[r * HD + f]);
    }
    agg[n * HD + f] = (s1 > s0) ? m : 0.0f; // PyG: empty segment -> 0
}

// ------- out = h + bl + agg @ wlT + h @ wrT  (optionally ReLU) --------
__global__ void combine_k(const float* __restrict__ h, const float* __restrict__ agg,
                          const float* __restrict__ wlT, const float* __restrict__ bl,
                          const float* __restrict__ wrT, float* __restrict__ out,
                          int relu) {
    int col  = threadIdx.x;                 // 128 threads
    int row0 = blockIdx.x * RROWS;
    float acc[RROWS];
    #pragma unroll
    for (int r = 0; r < RROWS; ++r) acc[r] = 0.0f;
    #pragma unroll 4
    for (int k = 0; k < HD; ++k) {
        float wlv = wlT[k * HD + col];
        float wrv = wrT[k * HD + col];
        #pragma unroll
        for (int r = 0; r < RROWS; ++r) {
            acc[r] += agg[(row0 + r) * HD + k] * wlv;  // uniform -> s_load
            acc[r] += h[(row0 + r) * HD + k] * wrv;    // uniform -> s_load
        }
    }
    float b = bl[col];
    #pragma unroll
    for (int r = 0; r < RROWS; ++r) {
        float v = h[(row0 + r) * HD + col] + b + acc[r];
        out[(row0 + r) * HD + col] = relu ? fmaxf(v, 0.0f) : v;
    }
}

extern "C" void kernel_launch(void* const* d_in, const int* in_sizes, int n_in,
                              void* d_out, int out_size, void* d_ws, size_t ws_size,
                              hipStream_t stream) {
    const float* x    = (const float*)d_in[0];
    const int*   ei   = (const int*)d_in[1];       // [2][E]: src row 0, dst row 1
    // d_in[2] node_type: layout known (first NUSR users) -> unused
    const float* w_user = (const float*)d_in[3];
    const float* b_user = (const float*)d_in[4];
    const float* w_item = (const float*)d_in[5];
    const float* b_item = (const float*)d_in[6];
    const float* w_l0   = (const float*)d_in[7];
    const float* b_l0   = (const float*)d_in[8];
    const float* w_r0   = (const float*)d_in[9];
    const float* w_l1   = (const float*)d_in[10];
    const float* b_l1   = (const float*)d_in[11];
    const float* w_r1   = (const float*)d_in[12];

    const int* e_src = ei;
    const int* e_dst = ei + EE;

    // ---- workspace carve-up (256B aligned) ----
    char* ws = (char*)d_ws;
    size_t cur_off = 0;
    auto carve = [&](size_t bytes) {
        void* p = ws + cur_off;
        cur_off = (cur_off + bytes + 255) & ~(size_t)255;
        return p;
    };
    float* h0    = (float*)carve((size_t)NN * HD * 4);   // 51.2 MB (also h2 later)
    float* aggb  = (float*)carve((size_t)NN * HD * 4);   // 51.2 MB
    float* wuT   = (float*)carve(HD * HD * 4);
    float* wiT   = (float*)carve(HD * HD * 4);
    float* wl0T  = (float*)carve(HD * HD * 4);
    float* wr0T  = (float*)carve(HD * HD * 4);
    float* wl1T  = (float*)carve(HD * HD * 4);
    float* wr1T  = (float*)carve(HD * HD * 4);
    int*   off   = (int*)carve((size_t)(NN + 1) * 4);
    int*   curp  = (int*)carve((size_t)NN * 4);
    int*   cnt   = (int*)carve((size_t)NN * 4);
    int*   bsum  = (int*)carve(128 * 4);
    int*   bbase = (int*)carve(128 * 4);
    int*   csr   = (int*)carve((size_t)EE * 4);          // 8 MB
    (void)ws_size;

    // ---- weight transposes ----
    dim3 tgrid(4, 4), tblk(32, 8);
    transpose128<<<tgrid, tblk, 0, stream>>>(w_user, wuT);
    transpose128<<<tgrid, tblk, 0, stream>>>(w_item, wiT);
    transpose128<<<tgrid, tblk, 0, stream>>>(w_l0, wl0T);
    transpose128<<<tgrid, tblk, 0, stream>>>(w_r0, wr0T);
    transpose128<<<tgrid, tblk, 0, stream>>>(w_l1, wl1T);
    transpose128<<<tgrid, tblk, 0, stream>>>(w_r1, wr1T);

    // ---- CSR build (by dst) ----
    hipMemsetAsync(cnt, 0, (size_t)NN * 4, stream);
    int eblocks = (EE + 255) / 256;
    count_k<<<eblocks, 256, 0, stream>>>(e_dst, cnt, EE);
    int nb = (NN + 1023) / 1024;                          // 98
    scan1_k<<<nb, 1024, 0, stream>>>(cnt, off, bsum, NN);
    scan2_k<<<1, 128, 0, stream>>>(bsum, bbase, nb, off, NN);
    scan3_k<<<nb, 1024, 0, stream>>>(off, bbase, curp, NN);
    scatter_k<<<eblocks, 256, 0, stream>>>(e_src, e_dst, curp, csr, EE);

    // ---- input projection ----
    proj_k<<<NN / RROWS, HD, 0, stream>>>(x, wuT, b_user, wiT, b_item, h0);

    // ---- layer 0: h1 = relu(h0 + conv0(h0)) -> d_out ----
    float* h1 = (float*)d_out;
    agg_k<<<NN, HD, 0, stream>>>(h0, off, csr, aggb);
    combine_k<<<NN / RROWS, HD, 0, stream>>>(h0, aggb, wl0T, b_l0, wr0T, h1, 1);

    // ---- layer 1: h2 = h1 + conv1(h1) -> h0 buffer (h0 dead), then copy out ----
    agg_k<<<NN, HD, 0, stream>>>(h1, off, csr, aggb);
    combine_k<<<NN / RROWS, HD, 0, stream>>>(h1, aggb, wl1T, b_l1, wr1T, h0, 0);
    hipMemcpyAsync(d_out, h0, (size_t)NN * HD * 4, hipMemcpyDeviceToDevice, stream);
}

// Round 2
// 543.102 us; speedup vs baseline: 2.0210x; 2.0210x over previous
//
#include <hip/hip_runtime.h>

#define NUSR 60000
#define NITM 40000
#define NN   100000
#define EE   2000000
#define HD   128
#define NEG_BIG (-3.402823466e+38f)

using bf16x8   = __attribute__((ext_vector_type(8))) short;
using f32x4    = __attribute__((ext_vector_type(4))) float;
using ushort4t = __attribute__((ext_vector_type(4))) unsigned short;

__device__ __forceinline__ unsigned short f2bf(float f) {
    unsigned int u = __float_as_uint(f);
    u += 0x7FFFu + ((u >> 16) & 1u);           // round-to-nearest-even
    return (unsigned short)(u >> 16);
}
__device__ __forceinline__ float bf2f(unsigned short s) {
    return __uint_as_float(((unsigned int)s) << 16);
}
// LDS swizzle: logical (row, col) in ushort units -> conflict-free index
__device__ __forceinline__ int swz(int row, int col) {
    return row * HD + (col ^ ((row & 7) << 3));
}

// ---------------- CSR build ----------------
__global__ void count_k(const int* __restrict__ dst, int* __restrict__ cnt, int e) {
    int i = blockIdx.x * blockDim.x + threadIdx.x;
    if (i < e) atomicAdd(&cnt[dst[i]], 1);
}

__global__ void scan1_k(const int* __restrict__ cnt, int* __restrict__ off,
                        int* __restrict__ bsum, int n) {
    __shared__ int s[1024];
    int t = threadIdx.x;
    int i = blockIdx.x * 1024 + t;
    int v = (i < n) ? cnt[i] : 0;
    s[t] = v;
    __syncthreads();
    for (int d = 1; d < 1024; d <<= 1) {
        int add = (t >= d) ? s[t - d] : 0;
        __syncthreads();
        s[t] += add;
        __syncthreads();
    }
    if (i < n) off[i] = s[t] - v;
    if (t == 1023) bsum[blockIdx.x] = s[1023];
}

__global__ void scan2_k(const int* __restrict__ bsum, int* __restrict__ bbase,
                        int nb, int* __restrict__ off, int n) {
    __shared__ int s[128];
    int t = threadIdx.x;
    int v = (t < nb) ? bsum[t] : 0;
    s[t] = v;
    __syncthreads();
    for (int d = 1; d < 128; d <<= 1) {
        int add = (t >= d) ? s[t - d] : 0;
        __syncthreads();
        s[t] += add;
        __syncthreads();
    }
    if (t < nb) bbase[t] = s[t] - v;
    if (t == 127) off[n] = s[127];
}

__global__ void scan3_k(int* __restrict__ off, const int* __restrict__ bbase,
                        int* __restrict__ cur, int n) {
    int i = blockIdx.x * 1024 + threadIdx.x;
    if (i < n) {
        int o = off[i] + bbase[blockIdx.x];
        off[i] = o;
        cur[i] = o;
    }
}

__global__ void scatter_k(const int* __restrict__ src, const int* __restrict__ dst,
                          int* __restrict__ cur, int* __restrict__ csr, int e) {
    int i = blockIdx.x * blockDim.x + threadIdx.x;
    if (i < e) {
        int p = atomicAdd(&cur[dst[i]], 1);
        csr[p] = src[i];
    }
}

// ---------------- fp32 -> bf16 weight convert (6 mats of 128x128) ------------
__global__ void cvt6_k(const float* __restrict__ a0, const float* __restrict__ a1,
                       const float* __restrict__ a2, const float* __restrict__ a3,
                       const float* __restrict__ a4, const float* __restrict__ a5,
                       unsigned short* __restrict__ out) {
    int i = blockIdx.x * 256 + threadIdx.x;      // 6*16384 total
    const float* s;
    switch (i >> 14) {
        case 0: s = a0; break; case 1: s = a1; break; case 2: s = a2; break;
        case 3: s = a3; break; case 4: s = a4; break; default: s = a5; break;
    }
    out[i] = f2bf(s[i & 16383]);
}

// -------- proj: h[row_base+r] = bf16( x[row_base+r] @ w.T + b ), MFMA --------
__global__ __launch_bounds__(256) void proj_mfma_k(
    const float* __restrict__ x, const unsigned short* __restrict__ wb,
    const float* __restrict__ bias, unsigned short* __restrict__ hout,
    int row_base, int nrows) {
    __shared__ unsigned short lw[HD * HD];       // 32 KB, swizzled [n][k]
    int tid = threadIdx.x;
    #pragma unroll
    for (int it = 0; it < 16; ++it) {
        int flat = (it * 256 + tid) * 4;
        int row = flat >> 7, col = flat & 127;
        *(ushort4t*)&lw[swz(row, col)] = *(const ushort4t*)(wb + flat);
    }
    __syncthreads();
    int lane = tid & 63, w = tid >> 6;
    int l15 = lane & 15, l4 = lane >> 4;
    int m0 = blockIdx.x * 128 + w * 32;          // local row of this wave
    f32x4 acc[2][8] = {};
    #pragma unroll
    for (int kb = 0; kb < 4; ++kb) {
        bf16x8 a[2];
        #pragma unroll
        for (int rt = 0; rt < 2; ++rt) {
            int r = m0 + rt * 16 + l15;
            if (r >= nrows) r = nrows - 1;       // clamp (masked on store)
            const float* ap = x + (size_t)(row_base + r) * HD + kb * 32 + l4 * 8;
            f32x4 v0 = *(const f32x4*)ap;
            f32x4 v1 = *(const f32x4*)(ap + 4);
            bf16x8 f;
            #pragma unroll
            for (int j = 0; j < 4; ++j) { f[j] = (short)f2bf(v0[j]); f[j + 4] = (short)f2bf(v1[j]); }
            a[rt] = f;
        }
        #pragma unroll
        for (int ct = 0; ct < 8; ++ct) {
            bf16x8 b = *(const bf16x8*)&lw[swz(ct * 16 + l15, kb * 32 + l4 * 8)];
            acc[0][ct] = __builtin_amdgcn_mfma_f32_16x16x32_bf16(a[0], b, acc[0][ct], 0, 0, 0);
            acc[1][ct] = __builtin_amdgcn_mfma_f32_16x16x32_bf16(a[1], b, acc[1][ct], 0, 0, 0);
        }
    }
    #pragma unroll
    for (int ct = 0; ct < 8; ++ct) {
        int col = ct * 16 + l15;
        float bv = bias[col];
        #pragma unroll
        for (int rt = 0; rt < 2; ++rt)
            #pragma unroll
            for (int j = 0; j < 4; ++j) {
                int r = m0 + rt * 16 + l4 * 4 + j;
                if (r < nrows)
                    hout[(size_t)(row_base + r) * HD + col] = f2bf(acc[rt][ct][j] + bv);
            }
    }
}

// ---------------- segment max over in-edges (bf16, wave per node) ------------
__global__ __launch_bounds__(256) void agg_bf16_k(
    const unsigned short* __restrict__ hb, const int* __restrict__ off,
    const int* __restrict__ csr, unsigned short* __restrict__ aggb) {
    int node = (blockIdx.x * 256 + threadIdx.x) >> 6;
    int lane = threadIdx.x & 63;
    if (node >= NN) return;
    int s0 = off[node], s1 = off[node + 1];
    const unsigned int* hr = (const unsigned int*)hb;   // ushort2 per lane
    float m0 = NEG_BIG, m1 = NEG_BIG;
    int j = s0;
    for (; j + 3 < s1; j += 4) {
        int r0 = csr[j], r1 = csr[j + 1], r2 = csr[j + 2], r3 = csr[j + 3];
        unsigned v0 = hr[(size_t)r0 * 64 + lane];
        unsigned v1 = hr[(size_t)r1 * 64 + lane];
        unsigned v2 = hr[(size_t)r2 * 64 + lane];
        unsigned v3 = hr[(size_t)r3 * 64 + lane];
        m0 = fmaxf(fmaxf(m0, __uint_as_float(v0 << 16)), fmaxf(__uint_as_float(v1 << 16), __uint_as_float(v2 << 16)));
        m1 = fmaxf(fmaxf(m1, __uint_as_float(v0 & 0xFFFF0000u)), fmaxf(__uint_as_float(v1 & 0xFFFF0000u), __uint_as_float(v2 & 0xFFFF0000u)));
        m0 = fmaxf(m0, __uint_as_float(v3 << 16));
        m1 = fmaxf(m1, __uint_as_float(v3 & 0xFFFF0000u));
    }
    for (; j < s1; ++j) {
        unsigned v = hr[(size_t)csr[j] * 64 + lane];
        m0 = fmaxf(m0, __uint_as_float(v << 16));
        m1 = fmaxf(m1, __uint_as_float(v & 0xFFFF0000u));
    }
    // maxima of bf16 values are exact bf16 -> truncation is lossless
    unsigned outv = (s1 > s0) ? ((__float_as_uint(m0) >> 16) | (__float_as_uint(m1) & 0xFFFF0000u)) : 0u;
    ((unsigned int*)aggb)[(size_t)node * 64 + lane] = outv;
}

// ----- combine: out = h + bl + agg@wl.T + h@wr.T  (relu?) via 2 fused MFMA ---
__global__ __launch_bounds__(256) void combine_mfma_k(
    const unsigned short* __restrict__ hb, const unsigned short* __restrict__ aggb,
    const unsigned short* __restrict__ wlb, const float* __restrict__ bl,
    const unsigned short* __restrict__ wrb,
    unsigned short* __restrict__ hnext, float* __restrict__ fout, int relu) {
    __shared__ unsigned short lw[2][HD * HD];    // 64 KB, swizzled
    int tid = threadIdx.x;
    #pragma unroll
    for (int it = 0; it < 16; ++it) {
        int flat = (it * 256 + tid) * 4;
        int row = flat >> 7, col = flat & 127;
        *(ushort4t*)&lw[0][swz(row, col)] = *(const ushort4t*)(wlb + flat);
        *(ushort4t*)&lw[1][swz(row, col)] = *(const ushort4t*)(wrb + flat);
    }
    __syncthreads();
    int lane = tid & 63, w = tid >> 6;
    int l15 = lane & 15, l4 = lane >> 4;
    int m0 = blockIdx.x * 128 + w * 32;
    f32x4 acc[2][8] = {};
    #pragma unroll
    for (int kb = 0; kb < 4; ++kb) {
        bf16x8 a1[2], a2[2];
        #pragma unroll
        for (int rt = 0; rt < 2; ++rt) {
            int r = m0 + rt * 16 + l15;
            if (r >= NN) r = NN - 1;
            size_t o = (size_t)r * HD + kb * 32 + l4 * 8;
            a1[rt] = *(const bf16x8*)(aggb + o);
            a2[rt] = *(const bf16x8*)(hb + o);
        }
        #pragma unroll
        for (int ct = 0; ct < 8; ++ct) {
            bf16x8 b1 = *(const bf16x8*)&lw[0][swz(ct * 16 + l15, kb * 32 + l4 * 8)];
            bf16x8 b2 = *(const bf16x8*)&lw[1][swz(ct * 16 + l15, kb * 32 + l4 * 8)];
            acc[0][ct] = __builtin_amdgcn_mfma_f32_16x16x32_bf16(a1[0], b1, acc[0][ct], 0, 0, 0);
            acc[0][ct] = __builtin_amdgcn_mfma_f32_16x16x32_bf16(a2[0], b2, acc[0][ct], 0, 0, 0);
            acc[1][ct] = __builtin_amdgcn_mfma_f32_16x16x32_bf16(a1[1], b1, acc[1][ct], 0, 0, 0);
            acc[1][ct] = __builtin_amdgcn_mfma_f32_16x16x32_bf16(a2[1], b2, acc[1][ct], 0, 0, 0);
        }
    }
    #pragma unroll
    for (int ct = 0; ct < 8; ++ct) {
        int col = ct * 16 + l15;
        float bv = bl[col];
        #pragma unroll
        for (int rt = 0; rt < 2; ++rt)
            #pragma unroll
            for (int j = 0; j < 4; ++j) {
                int r = m0 + rt * 16 + l4 * 4 + j;
                if (r < NN) {
                    float v = acc[rt][ct][j] + bv + bf2f(hb[(size_t)r * HD + col]);
                    if (relu) v = fmaxf(v, 0.0f);
                    if (fout) fout[(size_t)r * HD + col] = v;
                    else      hnext[(size_t)r * HD + col] = f2bf(v);
                }
            }
    }
}

extern "C" void kernel_launch(void* const* d_in, const int* in_sizes, int n_in,
                              void* d_out, int out_size, void* d_ws, size_t ws_size,
                              hipStream_t stream) {
    const float* x      = (const float*)d_in[0];
    const int*   ei     = (const int*)d_in[1];
    const float* w_user = (const float*)d_in[3];
    const float* b_user = (const float*)d_in[4];
    const float* w_item = (const float*)d_in[5];
    const float* b_item = (const float*)d_in[6];
    const float* w_l0   = (const float*)d_in[7];
    const float* b_l0   = (const float*)d_in[8];
    const float* w_r0   = (const float*)d_in[9];
    const float* w_l1   = (const float*)d_in[10];
    const float* b_l1   = (const float*)d_in[11];
    const float* w_r1   = (const float*)d_in[12];

    const int* e_src = ei;
    const int* e_dst = ei + EE;

    char* ws = (char*)d_ws;
    size_t cur_off = 0;
    auto carve = [&](size_t bytes) {
        void* p = ws + cur_off;
        cur_off = (cur_off + bytes + 255) & ~(size_t)255;
        return p;
    };
    unsigned short* hb0  = (unsigned short*)carve((size_t)NN * HD * 2);  // 25.6 MB
    unsigned short* hb1  = (unsigned short*)carve((size_t)NN * HD * 2);
    unsigned short* aggb = (unsigned short*)carve((size_t)NN * HD * 2);
    unsigned short* wb   = (unsigned short*)carve((size_t)6 * HD * HD * 2);
    int* off   = (int*)carve((size_t)(NN + 1) * 4);
    int* curp  = (int*)carve((size_t)NN * 4);
    int* cnt   = (int*)carve((size_t)NN * 4);
    int* bsum  = (int*)carve(128 * 4);
    int* bbase = (int*)carve(128 * 4);
    int* csr   = (int*)carve((size_t)EE * 4);
    (void)ws_size;

    // ---- CSR build (by dst) ----
    hipMemsetAsync(cnt, 0, (size_t)NN * 4, stream);
    int eblocks = (EE + 255) / 256;
    count_k<<<eblocks, 256, 0, stream>>>(e_dst, cnt, EE);
    int nb = (NN + 1023) / 1024;
    scan1_k<<<nb, 1024, 0, stream>>>(cnt, off, bsum, NN);
    scan2_k<<<1, 128, 0, stream>>>(bsum, bbase, nb, off, NN);
    scan3_k<<<nb, 1024, 0, stream>>>(off, bbase, curp, NN);
    scatter_k<<<eblocks, 256, 0, stream>>>(e_src, e_dst, curp, csr, EE);

    // ---- weights -> bf16 ----
    cvt6_k<<<(6 * HD * HD) / 256, 256, 0, stream>>>(w_user, w_item, w_l0, w_r0, w_l1, w_r1, wb);

    // ---- input projection (per node type) ----
    proj_mfma_k<<<(NUSR + 127) / 128, 256, 0, stream>>>(x, wb,             b_user, hb0, 0,    NUSR);
    proj_mfma_k<<<(NITM + 127) / 128, 256, 0, stream>>>(x, wb + 16384,     b_item, hb0, NUSR, NITM);

    // ---- layer 0 ----
    agg_bf16_k<<<NN / 4, 256, 0, stream>>>(hb0, off, csr, aggb);
    combine_mfma_k<<<(NN + 127) / 128, 256, 0, stream>>>(
        hb0, aggb, wb + 2 * 16384, b_l0, wb + 3 * 16384, hb1, nullptr, 1);

    // ---- layer 1 ----
    agg_bf16_k<<<NN / 4, 256, 0, stream>>>(hb1, off, csr, aggb);
    combine_mfma_k<<<(NN + 127) / 128, 256, 0, stream>>>(
        hb1, aggb, wb + 4 * 16384, b_l1, wb + 5 * 16384, nullptr, (float*)d_out, 0);
}

// Round 3
// 355.528 us; speedup vs baseline: 3.0872x; 1.5276x over previous
//
#include <hip/hip_runtime.h>

#define NUSR 60000
#define NITM 40000
#define NN   100000
#define EE   2000000
#define HD   128
#define NEG_BIG (-3.402823466e+38f)

#define BW   512                 // bucket width in nodes
#define NB   196                 // ceil(NN / BW)
#define EPB  8192                // edges per block in binning kernels

using bf16x8   = __attribute__((ext_vector_type(8))) short;
using f32x4    = __attribute__((ext_vector_type(4))) float;
using ushort4t = __attribute__((ext_vector_type(4))) unsigned short;

__device__ __forceinline__ unsigned short f2bf(float f) {
    unsigned int u = __float_as_uint(f);
    u += 0x7FFFu + ((u >> 16) & 1u);           // round-to-nearest-even
    return (unsigned short)(u >> 16);
}
__device__ __forceinline__ float bf2f(unsigned short s) {
    return __uint_as_float(((unsigned int)s) << 16);
}
__device__ __forceinline__ int swz(int row, int col) {
    return row * HD + (col ^ ((row & 7) << 3));
}

// ---------------- CSR build via 2-level bucket binning ----------------
__global__ __launch_bounds__(256) void bhist_k(const int* __restrict__ dst,
                                               int* __restrict__ bcnt) {
    __shared__ int h[NB];
    int t = threadIdx.x;
    if (t < NB) h[t] = 0;
    __syncthreads();
    int e0 = blockIdx.x * EPB;
    #pragma unroll 4
    for (int i = t; i < EPB; i += 256) {
        int e = e0 + i;
        if (e < EE) atomicAdd(&h[dst[e] >> 9], 1);
    }
    __syncthreads();
    if (t < NB && h[t]) atomicAdd(&bcnt[t], h[t]);
}

__global__ void bscan_k(const int* __restrict__ bcnt, int* __restrict__ bbase,
                        int* __restrict__ bcur, int* __restrict__ off) {
    __shared__ int s[256];
    int t = threadIdx.x;
    int v = (t < NB) ? bcnt[t] : 0;
    s[t] = v;
    __syncthreads();
    for (int d = 1; d < 256; d <<= 1) {
        int a = (t >= d) ? s[t - d] : 0;
        __syncthreads();
        s[t] += a;
        __syncthreads();
    }
    if (t < NB) { bbase[t] = s[t] - v; bcur[t] = s[t] - v; }
    if (t == NB - 1) { bbase[NB] = s[t]; off[NN] = EE; }
}

__global__ __launch_bounds__(256) void bscatter_k(const int* __restrict__ src,
                                                  const int* __restrict__ dst,
                                                  int* __restrict__ bcur,
                                                  uint2* __restrict__ bedge) {
    __shared__ int h[NB], base[NB];
    int t = threadIdx.x;
    if (t < NB) h[t] = 0;
    __syncthreads();
    int e0 = blockIdx.x * EPB;
    #pragma unroll 4
    for (int i = t; i < EPB; i += 256) {
        int e = e0 + i;
        if (e < EE) atomicAdd(&h[dst[e] >> 9], 1);
    }
    __syncthreads();
    if (t < NB) {
        int c = h[t];
        base[t] = c ? atomicAdd(&bcur[t], c) : 0;
        h[t] = 0;
    }
    __syncthreads();
    #pragma unroll 4
    for (int i = t; i < EPB; i += 256) {
        int e = e0 + i;
        if (e < EE) {
            int d = dst[e];
            int b = d >> 9;
            int p = base[b] + atomicAdd(&h[b], 1);
            bedge[p] = make_uint2((unsigned)src[e], (unsigned)d);
        }
    }
}

// one block per bucket: per-node counts + scan in LDS -> off[], then scatter
// into an L2-resident CSR window.
__global__ __launch_bounds__(512) void bcsr_k(const uint2* __restrict__ bedge,
                                              const int* __restrict__ bbase,
                                              int* __restrict__ off,
                                              int* __restrict__ csr) {
    __shared__ int cnt[BW], cur[BW], sc[BW];
    int b = blockIdx.x, t = threadIdx.x;
    int n0 = b * BW;
    int nloc = min(BW, NN - n0);
    cnt[t] = 0;
    __syncthreads();
    int e0 = bbase[b], e1 = bbase[b + 1];
    for (int e = e0 + t; e < e1; e += 512)
        atomicAdd(&cnt[(int)bedge[e].y - n0], 1);
    __syncthreads();
    int v = cnt[t];
    sc[t] = v;
    __syncthreads();
    for (int d = 1; d < BW; d <<= 1) {
        int a = (t >= d) ? sc[t - d] : 0;
        __syncthreads();
        sc[t] += a;
        __syncthreads();
    }
    int excl = sc[t] - v;
    if (t < nloc) { off[n0 + t] = e0 + excl; cur[t] = e0 + excl; }
    __syncthreads();
    for (int e = e0 + t; e < e1; e += 512) {
        uint2 ed = bedge[e];
        int p = atomicAdd(&cur[(int)ed.y - n0], 1);
        csr[p] = (int)ed.x;
    }
}

// ---------------- fp32 -> bf16 weight convert (6 mats of 128x128) ------------
__global__ void cvt6_k(const float* __restrict__ a0, const float* __restrict__ a1,
                       const float* __restrict__ a2, const float* __restrict__ a3,
                       const float* __restrict__ a4, const float* __restrict__ a5,
                       unsigned short* __restrict__ out) {
    int i = blockIdx.x * 256 + threadIdx.x;
    const float* s;
    switch (i >> 14) {
        case 0: s = a0; break; case 1: s = a1; break; case 2: s = a2; break;
        case 3: s = a3; break; case 4: s = a4; break; default: s = a5; break;
    }
    out[i] = f2bf(s[i & 16383]);
}

// -------- proj: h[row_base+r] = bf16( x[row_base+r] @ w.T + b ), MFMA --------
__global__ __launch_bounds__(256) void proj_mfma_k(
    const float* __restrict__ x, const unsigned short* __restrict__ wb,
    const float* __restrict__ bias, unsigned short* __restrict__ hout,
    int row_base, int nrows) {
    __shared__ unsigned short lw[HD * HD];
    int tid = threadIdx.x;
    #pragma unroll
    for (int it = 0; it < 16; ++it) {
        int flat = (it * 256 + tid) * 4;
        int row = flat >> 7, col = flat & 127;
        *(ushort4t*)&lw[swz(row, col)] = *(const ushort4t*)(wb + flat);
    }
    __syncthreads();
    int lane = tid & 63, w = tid >> 6;
    int l15 = lane & 15, l4 = lane >> 4;
    int m0 = blockIdx.x * 128 + w * 32;
    f32x4 acc[2][8] = {};
    #pragma unroll
    for (int kb = 0; kb < 4; ++kb) {
        bf16x8 a[2];
        #pragma unroll
        for (int rt = 0; rt < 2; ++rt) {
            int r = m0 + rt * 16 + l15;
            if (r >= nrows) r = nrows - 1;
            const float* ap = x + (size_t)(row_base + r) * HD + kb * 32 + l4 * 8;
            f32x4 v0 = *(const f32x4*)ap;
            f32x4 v1 = *(const f32x4*)(ap + 4);
            bf16x8 f;
            #pragma unroll
            for (int j = 0; j < 4; ++j) { f[j] = (short)f2bf(v0[j]); f[j + 4] = (short)f2bf(v1[j]); }
            a[rt] = f;
        }
        #pragma unroll
        for (int ct = 0; ct < 8; ++ct) {
            bf16x8 b = *(const bf16x8*)&lw[swz(ct * 16 + l15, kb * 32 + l4 * 8)];
            acc[0][ct] = __builtin_amdgcn_mfma_f32_16x16x32_bf16(a[0], b, acc[0][ct], 0, 0, 0);
            acc[1][ct] = __builtin_amdgcn_mfma_f32_16x16x32_bf16(a[1], b, acc[1][ct], 0, 0, 0);
        }
    }
    #pragma unroll
    for (int ct = 0; ct < 8; ++ct) {
        int col = ct * 16 + l15;
        float bv = bias[col];
        #pragma unroll
        for (int rt = 0; rt < 2; ++rt)
            #pragma unroll
            for (int j = 0; j < 4; ++j) {
                int r = m0 + rt * 16 + l4 * 4 + j;
                if (r < nrows)
                    hout[(size_t)(row_base + r) * HD + col] = f2bf(acc[rt][ct][j] + bv);
            }
    }
}

// ---------------- segment max over in-edges (bf16, wave per node) ------------
__global__ __launch_bounds__(256) void agg_bf16_k(
    const unsigned short* __restrict__ hb, const int* __restrict__ off,
    const int* __restrict__ csr, unsigned short* __restrict__ aggb) {
    int node = (blockIdx.x * 256 + threadIdx.x) >> 6;
    int lane = threadIdx.x & 63;
    if (node >= NN) return;
    int s0 = off[node], s1 = off[node + 1];
    const unsigned int* hr = (const unsigned int*)hb;
    float m0 = NEG_BIG, m1 = NEG_BIG;
    int j = s0;
    for (; j + 3 < s1; j += 4) {
        int r0 = csr[j], r1 = csr[j + 1], r2 = csr[j + 2], r3 = csr[j + 3];
        unsigned v0 = hr[(size_t)r0 * 64 + lane];
        unsigned v1 = hr[(size_t)r1 * 64 + lane];
        unsigned v2 = hr[(size_t)r2 * 64 + lane];
        unsigned v3 = hr[(size_t)r3 * 64 + lane];
        m0 = fmaxf(fmaxf(m0, __uint_as_float(v0 << 16)), fmaxf(__uint_as_float(v1 << 16), __uint_as_float(v2 << 16)));
        m1 = fmaxf(fmaxf(m1, __uint_as_float(v0 & 0xFFFF0000u)), fmaxf(__uint_as_float(v1 & 0xFFFF0000u), __uint_as_float(v2 & 0xFFFF0000u)));
        m0 = fmaxf(m0, __uint_as_float(v3 << 16));
        m1 = fmaxf(m1, __uint_as_float(v3 & 0xFFFF0000u));
    }
    for (; j < s1; ++j) {
        unsigned v = hr[(size_t)csr[j] * 64 + lane];
        m0 = fmaxf(m0, __uint_as_float(v << 16));
        m1 = fmaxf(m1, __uint_as_float(v & 0xFFFF0000u));
    }
    unsigned outv = (s1 > s0) ? ((__float_as_uint(m0) >> 16) | (__float_as_uint(m1) & 0xFFFF0000u)) : 0u;
    ((unsigned int*)aggb)[(size_t)node * 64 + lane] = outv;
}

// ----- combine: out = h + bl + agg@wl.T + h@wr.T  (relu?) via 2 fused MFMA ---
__global__ __launch_bounds__(256) void combine_mfma_k(
    const unsigned short* __restrict__ hb, const unsigned short* __restrict__ aggb,
    const unsigned short* __restrict__ wlb, const float* __restrict__ bl,
    const unsigned short* __restrict__ wrb,
    unsigned short* __restrict__ hnext, float* __restrict__ fout, int relu) {
    __shared__ unsigned short lw[2][HD * HD];
    int tid = threadIdx.x;
    #pragma unroll
    for (int it = 0; it < 16; ++it) {
        int flat = (it * 256 + tid) * 4;
        int row = flat >> 7, col = flat & 127;
        *(ushort4t*)&lw[0][swz(row, col)] = *(const ushort4t*)(wlb + flat);
        *(ushort4t*)&lw[1][swz(row, col)] = *(const ushort4t*)(wrb + flat);
    }
    __syncthreads();
    int lane = tid & 63, w = tid >> 6;
    int l15 = lane & 15, l4 = lane >> 4;
    int m0 = blockIdx.x * 128 + w * 32;
    f32x4 acc[2][8] = {};
    #pragma unroll
    for (int kb = 0; kb < 4; ++kb) {
        bf16x8 a1[2], a2[2];
        #pragma unroll
        for (int rt = 0; rt < 2; ++rt) {
            int r = m0 + rt * 16 + l15;
            if (r >= NN) r = NN - 1;
            size_t o = (size_t)r * HD + kb * 32 + l4 * 8;
            a1[rt] = *(const bf16x8*)(aggb + o);
            a2[rt] = *(const bf16x8*)(hb + o);
        }
        #pragma unroll
        for (int ct = 0; ct < 8; ++ct) {
            bf16x8 b1 = *(const bf16x8*)&lw[0][swz(ct * 16 + l15, kb * 32 + l4 * 8)];
            bf16x8 b2 = *(const bf16x8*)&lw[1][swz(ct * 16 + l15, kb * 32 + l4 * 8)];
            acc[0][ct] = __builtin_amdgcn_mfma_f32_16x16x32_bf16(a1[0], b1, acc[0][ct], 0, 0, 0);
            acc[0][ct] = __builtin_amdgcn_mfma_f32_16x16x32_bf16(a2[0], b2, acc[0][ct], 0, 0, 0);
            acc[1][ct] = __builtin_amdgcn_mfma_f32_16x16x32_bf16(a1[1], b1, acc[1][ct], 0, 0, 0);
            acc[1][ct] = __builtin_amdgcn_mfma_f32_16x16x32_bf16(a2[1], b2, acc[1][ct], 0, 0, 0);
        }
    }
    #pragma unroll
    for (int ct = 0; ct < 8; ++ct) {
        int col = ct * 16 + l15;
        float bv = bl[col];
        #pragma unroll
        for (int rt = 0; rt < 2; ++rt)
            #pragma unroll
            for (int j = 0; j < 4; ++j) {
                int r = m0 + rt * 16 + l4 * 4 + j;
                if (r < NN) {
                    float v = acc[rt][ct][j] + bv + bf2f(hb[(size_t)r * HD + col]);
                    if (relu) v = fmaxf(v, 0.0f);
                    if (fout) fout[(size_t)r * HD + col] = v;
                    else      hnext[(size_t)r * HD + col] = f2bf(v);
                }
            }
    }
}

extern "C" void kernel_launch(void* const* d_in, const int* in_sizes, int n_in,
                              void* d_out, int out_size, void* d_ws, size_t ws_size,
                              hipStream_t stream) {
    const float* x      = (const float*)d_in[0];
    const int*   ei     = (const int*)d_in[1];
    const float* w_user = (const float*)d_in[3];
    const float* b_user = (const float*)d_in[4];
    const float* w_item = (const float*)d_in[5];
    const float* b_item = (const float*)d_in[6];
    const float* w_l0   = (const float*)d_in[7];
    const float* b_l0   = (const float*)d_in[8];
    const float* w_r0   = (const float*)d_in[9];
    const float* w_l1   = (const float*)d_in[10];
    const float* b_l1   = (const float*)d_in[11];
    const float* w_r1   = (const float*)d_in[12];

    const int* e_src = ei;
    const int* e_dst = ei + EE;

    char* ws = (char*)d_ws;
    size_t cur_off = 0;
    auto carve = [&](size_t bytes) {
        void* p = ws + cur_off;
        cur_off = (cur_off + bytes + 255) & ~(size_t)255;
        return p;
    };
    unsigned short* hb0  = (unsigned short*)carve((size_t)NN * HD * 2);  // 25.6 MB
    unsigned short* hb1  = (unsigned short*)carve((size_t)NN * HD * 2);
    unsigned short* aggb = (unsigned short*)carve((size_t)NN * HD * 2);
    unsigned short* wb   = (unsigned short*)carve((size_t)6 * HD * HD * 2);
    int*   off   = (int*)carve((size_t)(NN + 1) * 4);
    int*   csr   = (int*)carve((size_t)EE * 4);          // 8 MB
    uint2* bedge = (uint2*)carve((size_t)EE * 8);        // 16 MB
    int*   bcnt  = (int*)carve((NB + 1) * 4);
    int*   bbase = (int*)carve((NB + 1) * 4);
    int*   bcur  = (int*)carve((NB + 1) * 4);
    (void)ws_size;

    // ---- CSR build (bucket binning) ----
    hipMemsetAsync(bcnt, 0, (size_t)NB * 4, stream);
    int nbB = (EE + EPB - 1) / EPB;                       // 245
    bhist_k<<<nbB, 256, 0, stream>>>(e_dst, bcnt);
    bscan_k<<<1, 256, 0, stream>>>(bcnt, bbase, bcur, off);
    bscatter_k<<<nbB, 256, 0, stream>>>(e_src, e_dst, bcur, bedge);
    bcsr_k<<<NB, 512, 0, stream>>>(bedge, bbase, off, csr);

    // ---- weights -> bf16 ----
    cvt6_k<<<(6 * HD * HD) / 256, 256, 0, stream>>>(w_user, w_item, w_l0, w_r0, w_l1, w_r1, wb);

    // ---- input projection (per node type) ----
    proj_mfma_k<<<(NUSR + 127) / 128, 256, 0, stream>>>(x, wb,         b_user, hb0, 0,    NUSR);
    proj_mfma_k<<<(NITM + 127) / 128, 256, 0, stream>>>(x, wb + 16384, b_item, hb0, NUSR, NITM);

    // ---- layer 0 ----
    agg_bf16_k<<<NN / 4, 256, 0, stream>>>(hb0, off, csr, aggb);
    combine_mfma_k<<<(NN + 127) / 128, 256, 0, stream>>>(
        hb0, aggb, wb + 2 * 16384, b_l0, wb + 3 * 16384, hb1, nullptr, 1);

    // ---- layer 1 ----
    agg_bf16_k<<<NN / 4, 256, 0, stream>>>(hb1, off, csr, aggb);
    combine_mfma_k<<<(NN + 127) / 128, 256, 0, stream>>>(
        hb1, aggb, wb + 4 * 16384, b_l1, wb + 5 * 16384, nullptr, (float*)d_out, 0);
}